// Round 16
// baseline (45.553 us; speedup 1.0000x reference)
//
#include <hip/hip_runtime.h>
#include <stdint.h>

// Deformable 3x3 local correlation. f16 CHANNEL-QUAD packed LDS: 8B at
// col x of quad-plane q = (f16 ch[4q..4q+3][x]). One aligned ds_read_b128
// covers cols {x,x+1} x 4ch = both x-taps of one row -> 72 DS gathers per
// thread (was 144 pair / 288 f32). All 16 channels resident (4 quad-planes,
// 139KB LDS) -> 2 barriers, no double-buffer. fdot2 accumulates in f32.
// Per-s setup recomputed in-loop to fit the hard 64-VGPR cap (r6-r13:
// cap not overridable; WRITE_SIZE >> 9.2MB = spill tripwire).
// left/right (2,128,64,256) f32, extra_offset (2,18,64,256) f32,
// out (2,72,64,256) f32. GROUPS=8, cg=16, S=9.

#define NB 2
#define CC 128
#define HH 64
#define WW 256
#define GG 8
#define CG 16
#define SS 9
#define HW (HH * WW)
#define TY 4                      // output rows per block
#define RW 5                      // staged rows h0-RW .. h0+TY+RW-1 (14 interior)
#define NSLOT 16                  // 1 top guard + 14 data + 1 bottom guard
#define SLOTQW 544                // dwords per slot (257 cols x 2dw + pad; mult of 32)
#define B0 2                      // col x -> dword B0+2x (x=-1 -> dword 0)
#define PLANEQW (NSLOT * SLOTQW)  // 8704 dw per quad-plane
#define NQUAD 4                   // 4 channel quads = whole group
#define SMEMDW (NQUAD * PLANEQW)  // 34816 dw = 139.3 KB -> 1 block/CU

typedef __fp16 h2v __attribute__((ext_vector_type(2)));

static __device__ __forceinline__ uint32_t pkrtz(float a, float b) {
    h2v v = __builtin_amdgcn_cvt_pkrtz(a, b);
    return __builtin_bit_cast(uint32_t, v);
}
static __device__ __forceinline__ h2v u2h(uint32_t u) {
    return __builtin_bit_cast(h2v, u);
}

#if __has_builtin(__builtin_amdgcn_fdot2)
#define FDOT2(A, B, C) __builtin_amdgcn_fdot2((A), (B), (C), false)
#else
#define FDOT2(A, B, C) fmaf((float)(A).x, (float)(B).x, \
                            fmaf((float)(A).y, (float)(B).y, (C)))
#endif

__global__ __launch_bounds__(1024) void corr_kernel(
    const float* __restrict__ left, const float* __restrict__ right,
    const float* __restrict__ eo, float* __restrict__ out)
{
    __shared__ uint32_t smem[SMEMDW];

    const int tid = threadIdx.x;
    const int lane = tid & 63;
    const int wv = tid >> 6;                 // wave 0..15
    const int bid = blockIdx.x;
    const int g = bid & (GG - 1);
    const int h0 = ((bid >> 3) & 15) << 2;
    const int n = bid >> 7;
    const int gch = g * CG;

    const int virt_row0 = h0 - RW;                        // slot 1 maps here
    const int row0 = max(0, virt_row0);
    const int row_last = min(HH - 1, h0 + TY + RW - 1);   // h0+8 interior
    const int nrows = row_last - row0 + 1;                // <= 14
    const int sbase = row0 - virt_row0 + 1;

    const int hh = tid >> 8;                 // 0..3 (wave-uniform)
    const int h = h0 + hh;
    const int wcol = tid & 255;
    const int pix = h * WW + wcol;

    const float* rnb = right + (size_t)n * CC * HW;
    const float* lp  = left  + (size_t)(n * CC + gch) * HW + pix;
    const float* eob = eo + (size_t)n * SS * 2 * HW + pix;

    // zero LDS (guard slots/cols must read as f16 0.0 = 0x0000)
    for (int i = tid; i < SMEMDW / 4; i += 1024)
        *(uint4*)&smem[4 * i] = make_uint4(0u, 0u, 0u, 0u);
    __syncthreads();

    // stage 4 quad-planes: wave wv handles window row wv of each plane.
    // lane covers cols 4l..4l+3 (8B/col): 4x float4 load -> 8 pkrtz -> 2 b128.
#pragma unroll
    for (int q = 0; q < NQUAD; ++q) {
        if (wv < nrows) {
            const float* s0 = rnb + (size_t)(gch + 4 * q) * HW
                            + (row0 + wv) * WW + 4 * lane;
            const float4 a = *(const float4*)s0;
            const float4 b = *(const float4*)(s0 + HW);
            const float4 c = *(const float4*)(s0 + 2 * HW);
            const float4 d = *(const float4*)(s0 + 3 * HW);
            uint32_t* dst = &smem[q * PLANEQW + (sbase + wv) * SLOTQW
                                  + B0 + 8 * lane];
            uint4 o0, o1;
            o0.x = pkrtz(a.x, b.x); o0.y = pkrtz(c.x, d.x);
            o0.z = pkrtz(a.y, b.y); o0.w = pkrtz(c.y, d.y);
            o1.x = pkrtz(a.z, b.z); o1.y = pkrtz(c.z, d.z);
            o1.z = pkrtz(a.w, b.w); o1.w = pkrtz(c.w, d.w);
            *(uint4*)dst = o0;
            *(uint4*)(dst + 4) = o1;
        }
    }

    // left values, packed per quad: lvq[q] = {pk(c0,c1), pk(c2,c3)}
    uint32_t lvq[2 * NQUAD];
#pragma unroll
    for (int q = 0; q < NQUAD; ++q) {
        lvq[2 * q]     = pkrtz(lp[(size_t)(4 * q) * HW],
                               lp[(size_t)(4 * q + 1) * HW]);
        lvq[2 * q + 1] = pkrtz(lp[(size_t)(4 * q + 2) * HW],
                               lp[(size_t)(4 * q + 3) * HW]);
    }

    __syncthreads();                 // planes staged; no more barriers

    float acc[SS];
#pragma unroll
    for (int s = 0; s < SS; ++s) acc[s] = 0.0f;

    const char* sb = (const char*)smem;

#pragma unroll
    for (int s = 0; s < SS; ++s) {
        const float x = (float)(s / 3 - 1) + eob[(2 * s) * HW] + (float)wcol;
        const float y = (float)(s % 3 - 1) + eob[(2 * s + 1) * HW] + (float)h;
        const float x0f = floorf(x), y0f = floorf(y);
        const float fx0 = x - x0f, fx1 = 1.0f - fx0;
        const float fy0 = y - y0f, fy1 = 1.0f - fy0;
        const int x0 = (int)x0f, y0 = (int)y0f;
        const int x1 = x0 + 1,   y1 = y0 + 1;
        const bool vx0 = (unsigned)x0 < (unsigned)WW;
        const bool vx1 = (unsigned)x1 < (unsigned)WW;
        const bool vy0 = (unsigned)y0 < (unsigned)HH;
        const bool vy1 = (unsigned)y1 < (unsigned)HH;
        const float wA = (vx0 && vy0) ? fx1 * fy1 : 0.0f;   // (x0,y0)
        const float wB = (vx1 && vy0) ? fx0 * fy1 : 0.0f;   // (x1,y0)
        const float wC = (vx0 && vy1) ? fx1 * fy0 : 0.0f;   // (x0,y1)
        const float wD = (vx1 && vy1) ? fx0 * fy0 : 0.0f;   // (x1,y1)

        const bool bad = (vy0 && (y0 < row0 || y0 > row_last)) ||
                         (vy1 && (y1 < row0 || y1 > row_last));

        if (__builtin_expect(!bad, 1)) {
            const int xc = min(max(x0, -1), WW);                       // [-1,256]
            const int rr = min(max(y0 - virt_row0 + 1, 0), NSLOT - 2); // [0,14]
            const char* base = sb + (size_t)((rr * SLOTQW + B0 + 2 * xc) * 4);
            float t = 0.0f;
#pragma unroll
            for (int q = 0; q < NQUAD; ++q) {
                const char* bp = base + q * (PLANEQW * 4);
                const uint4 r0 = *(const uint4*)(bp);              // row y0: x0,x1
                const uint4 r1 = *(const uint4*)(bp + SLOTQW * 4); // row y1: x0,x1
                const h2v lv0 = u2h(lvq[2 * q]), lv1 = u2h(lvq[2 * q + 1]);
                t = fmaf(wA, FDOT2(u2h(r0.x), lv0, FDOT2(u2h(r0.y), lv1, 0.0f)), t);
                t = fmaf(wB, FDOT2(u2h(r0.z), lv0, FDOT2(u2h(r0.w), lv1, 0.0f)), t);
                t = fmaf(wC, FDOT2(u2h(r1.x), lv0, FDOT2(u2h(r1.y), lv1, 0.0f)), t);
                t = fmaf(wD, FDOT2(u2h(r1.z), lv0, FDOT2(u2h(r1.w), lv1, 0.0f)), t);
            }
            acc[s] += t;
        } else {
            // ~never (needs |eo| > ~4.5 sigma): full-precision global fallback
            const int cx0 = min(max(x0, 0), WW - 1), cx1 = min(max(x1, 0), WW - 1);
            const int cy0 = min(max(y0, 0), HH - 1), cy1 = min(max(y1, 0), HH - 1);
#pragma unroll
            for (int q = 0; q < NQUAD; ++q) {
                const h2v lv0 = u2h(lvq[2 * q]), lv1 = u2h(lvq[2 * q + 1]);
#pragma unroll
                for (int c2 = 0; c2 < 4; ++c2) {
                    const float* rp2 = rnb + (size_t)(gch + 4 * q + c2) * HW;
                    const float v = wA * rp2[cy0 * WW + cx0] + wB * rp2[cy0 * WW + cx1]
                                  + wC * rp2[cy1 * WW + cx0] + wD * rp2[cy1 * WW + cx1];
                    const float lvc = (c2 == 0) ? (float)lv0.x : (c2 == 1) ? (float)lv0.y
                                    : (c2 == 2) ? (float)lv1.x : (float)lv1.y;
                    acc[s] += lvc * v;
                }
            }
        }
    }

    float* ob = out + ((size_t)(n * GG + g) * SS) * HW + pix;
#pragma unroll
    for (int s = 0; s < SS; ++s)
        ob[s * HW] = acc[s] * (1.0f / CG);
}

extern "C" void kernel_launch(void* const* d_in, const int* in_sizes, int n_in,
                              void* d_out, int out_size, void* d_ws, size_t ws_size,
                              hipStream_t stream) {
    const float* left  = (const float*)d_in[0];
    const float* right = (const float*)d_in[1];
    const float* eo    = (const float*)d_in[2];
    float* out = (float*)d_out;
    (void)d_ws; (void)ws_size; (void)in_sizes; (void)n_in; (void)out_size;

    dim3 grid(NB * (HH / TY) * GG);   // 256 blocks: (n, h-tile, group)
    dim3 block(1024);                  // 16 waves; thread = (hh, w)
    corr_kernel<<<grid, block, 0, stream>>>(left, right, eo, out);
}

// Round 17
// 25.266 us; speedup vs baseline: 1.8030x; 1.8030x over previous
//
#include <hip/hip_runtime.h>
#include <stdint.h>

// Deformable 3x3 local correlation. f16 CHANNEL-PAIR packed LDS (r15 best,
// 25.4us) + explicit depth-1 software pipeline over pair-planes: plane p+1's
// two ds_read2 are in flight while plane p's fdot2 chain computes (the
// 64-VGPR cap kept the compiler from batching loads itself). Split t0/t1
// accumulators shorten the serial fma chain.
// r16 lesson: 8B-cell quad layout can't align b128 taps (dead end).
// r6-r13 lesson: 64-VGPR cap not overridable; WRITE_SIZE >> 9.2MB = spill.
// left/right (2,128,64,256) f32, extra_offset (2,18,64,256) f32,
// out (2,72,64,256) f32. GROUPS=8, cg=16, S=9.

#define NB 2
#define CC 128
#define HH 64
#define WW 256
#define GG 8
#define CG 16
#define SS 9
#define HW (HH * WW)
#define TY 4                      // output rows per block
#define RW 5                      // staged rows h0-RW .. h0+TY+RW-1 (14 interior)
#define NSLOT 16                  // 1 top guard + 14 data + 1 bottom guard
#define SLOTDW 288                // dwords per slot (mult of 32; 16B-aligned)
#define B0 4                      // col x -> dword B0+x  (x=-1 -> dword 3)
#define PLANEDW (NSLOT * SLOTDW)  // 4608 dw per pair-plane
#define NPAIR 8                   // 8 channel pairs = whole group
#define SMEMDW (NPAIR * PLANEDW)  // 36864 dw = 147.5 KB -> 1 block/CU

typedef __fp16 h2v __attribute__((ext_vector_type(2)));

static __device__ __forceinline__ uint32_t pkrtz(float a, float b) {
    h2v v = __builtin_amdgcn_cvt_pkrtz(a, b);
    return __builtin_bit_cast(uint32_t, v);
}
static __device__ __forceinline__ h2v u2h(uint32_t u) {
    return __builtin_bit_cast(h2v, u);
}

#if __has_builtin(__builtin_amdgcn_fdot2)
#define FDOT2(A, B, C) __builtin_amdgcn_fdot2((A), (B), (C), false)
#else
#define FDOT2(A, B, C) fmaf((float)(A).x, (float)(B).x, \
                            fmaf((float)(A).y, (float)(B).y, (C)))
#endif

// load pair-plane P's 4 taps into named regs (2x ds_read2_b32)
#define LOADP(P, Av, Bv, Cv, Dv)                                               \
  {                                                                            \
    const char* bp_ = base + (P) * (PLANEDW * 4);                              \
    Av = *(const h2v*)(bp_);                                                   \
    Bv = *(const h2v*)(bp_ + 4);                                               \
    Cv = *(const h2v*)(bp_ + SLOTDW * 4);                                      \
    Dv = *(const h2v*)(bp_ + SLOTDW * 4 + 4);                                  \
  }

// consume plane P's regs into accumulator T
#define USEP(P, Av, Bv, Cv, Dv, T)                                             \
  {                                                                            \
    const h2v lv_ = u2h(lvpk[P]);                                              \
    T = fmaf(wA, FDOT2(Av, lv_, 0.0f), T);                                     \
    T = fmaf(wB, FDOT2(Bv, lv_, 0.0f), T);                                     \
    T = fmaf(wC, FDOT2(Cv, lv_, 0.0f), T);                                     \
    T = fmaf(wD, FDOT2(Dv, lv_, 0.0f), T);                                     \
  }

__global__ __launch_bounds__(1024) void corr_kernel(
    const float* __restrict__ left, const float* __restrict__ right,
    const float* __restrict__ eo, float* __restrict__ out)
{
    __shared__ uint32_t smem[SMEMDW];

    const int tid = threadIdx.x;
    const int lane = tid & 63;
    const int wv = tid >> 6;                 // wave 0..15
    const int bid = blockIdx.x;
    const int g = bid & (GG - 1);
    const int h0 = ((bid >> 3) & 15) << 2;
    const int n = bid >> 7;
    const int gch = g * CG;

    const int virt_row0 = h0 - RW;                        // slot 1 maps here
    const int row0 = max(0, virt_row0);
    const int row_last = min(HH - 1, h0 + TY + RW - 1);   // h0+8 interior
    const int nrows = row_last - row0 + 1;                // <= 14
    const int sbase = row0 - virt_row0 + 1;

    const int hh = tid >> 8;                 // 0..3 (wave-uniform)
    const int h = h0 + hh;
    const int wcol = tid & 255;
    const int pix = h * WW + wcol;

    const float* rnb = right + (size_t)n * CC * HW;
    const float* lp  = left  + (size_t)(n * CC + gch) * HW + pix;
    const float* eob = eo + (size_t)n * SS * 2 * HW + pix;

    // zero LDS: guard slots/cols must read as 0.0 (f16 zero == 0x0000)
    for (int i = tid; i < SMEMDW / 4; i += 1024)
        *(uint4*)&smem[4 * i] = make_uint4(0u, 0u, 0u, 0u);
    __syncthreads();

    // stage all 8 pair-planes: wave wv handles window row wv of each plane.
    // lane covers cols 4l..4l+3: 2x float4 load -> 4x cvt_pkrtz -> b128 write.
#pragma unroll
    for (int p = 0; p < NPAIR; ++p) {
        if (wv < nrows) {
            const float* s0 = rnb + (size_t)(gch + 2 * p) * HW
                            + (row0 + wv) * WW + 4 * lane;
            const float4 a = *(const float4*)s0;
            const float4 b = *(const float4*)(s0 + HW);
            uint4 o;
            o.x = pkrtz(a.x, b.x);
            o.y = pkrtz(a.y, b.y);
            o.z = pkrtz(a.z, b.z);
            o.w = pkrtz(a.w, b.w);
            *(uint4*)&smem[p * PLANEDW + (sbase + wv) * SLOTDW + B0 + 4 * lane] = o;
        }
    }

    // left values, packed per pair
    uint32_t lvpk[NPAIR];
#pragma unroll
    for (int p = 0; p < NPAIR; ++p)
        lvpk[p] = pkrtz(lp[(size_t)(2 * p) * HW], lp[(size_t)(2 * p + 1) * HW]);

    __syncthreads();                 // planes staged; no more barriers

    float acc[SS];
#pragma unroll
    for (int s = 0; s < SS; ++s) acc[s] = 0.0f;

    const char* sb = (const char*)smem;

#pragma unroll
    for (int s = 0; s < SS; ++s) {
        const float x = (float)(s / 3 - 1) + eob[(2 * s) * HW] + (float)wcol;
        const float y = (float)(s % 3 - 1) + eob[(2 * s + 1) * HW] + (float)h;
        const float x0f = floorf(x), y0f = floorf(y);
        const float fx0 = x - x0f, fx1 = 1.0f - fx0;
        const float fy0 = y - y0f, fy1 = 1.0f - fy0;
        const int x0 = (int)x0f, y0 = (int)y0f;
        const int x1 = x0 + 1,   y1 = y0 + 1;
        const bool vx0 = (unsigned)x0 < (unsigned)WW;
        const bool vx1 = (unsigned)x1 < (unsigned)WW;
        const bool vy0 = (unsigned)y0 < (unsigned)HH;
        const bool vy1 = (unsigned)y1 < (unsigned)HH;
        const float wA = (vx0 && vy0) ? fx1 * fy1 : 0.0f;   // (x0,y0)
        const float wB = (vx1 && vy0) ? fx0 * fy1 : 0.0f;   // (x1,y0)
        const float wC = (vx0 && vy1) ? fx1 * fy0 : 0.0f;   // (x0,y1)
        const float wD = (vx1 && vy1) ? fx0 * fy0 : 0.0f;   // (x1,y1)

        const bool bad = (vy0 && (y0 < row0 || y0 > row_last)) ||
                         (vy1 && (y1 < row0 || y1 > row_last));

        if (__builtin_expect(!bad, 1)) {
            const int xc = min(max(x0, -1), WW);                       // [-1,256]
            const int rr = min(max(y0 - virt_row0 + 1, 0), NSLOT - 2); // [0,14]
            const char* base = sb + (size_t)((rr * SLOTDW + B0 + xc) * 4);

            // depth-1 pipelined plane loop: plane p+1 loads in flight
            // while plane p computes. Two named reg sets (rule: no
            // runtime-indexed arrays), two accumulators.
            h2v Aa, Ba, Ca, Da, Ab, Bb, Cb, Db;
            float t0 = 0.0f, t1 = 0.0f;
            LOADP(0, Aa, Ba, Ca, Da)
            LOADP(1, Ab, Bb, Cb, Db)
            USEP(0, Aa, Ba, Ca, Da, t0)
            LOADP(2, Aa, Ba, Ca, Da)
            USEP(1, Ab, Bb, Cb, Db, t1)
            LOADP(3, Ab, Bb, Cb, Db)
            USEP(2, Aa, Ba, Ca, Da, t0)
            LOADP(4, Aa, Ba, Ca, Da)
            USEP(3, Ab, Bb, Cb, Db, t1)
            LOADP(5, Ab, Bb, Cb, Db)
            USEP(4, Aa, Ba, Ca, Da, t0)
            LOADP(6, Aa, Ba, Ca, Da)
            USEP(5, Ab, Bb, Cb, Db, t1)
            LOADP(7, Ab, Bb, Cb, Db)
            USEP(6, Aa, Ba, Ca, Da, t0)
            USEP(7, Ab, Bb, Cb, Db, t1)
            acc[s] += t0 + t1;
        } else {
            // ~never (needs |eo| > ~4.5 sigma): full-precision global fallback
            const int cx0 = min(max(x0, 0), WW - 1), cx1 = min(max(x1, 0), WW - 1);
            const int cy0 = min(max(y0, 0), HH - 1), cy1 = min(max(y1, 0), HH - 1);
#pragma unroll
            for (int p = 0; p < NPAIR; ++p) {
                const h2v lv = u2h(lvpk[p]);
#pragma unroll
                for (int c2 = 0; c2 < 2; ++c2) {
                    const float* rp2 = rnb + (size_t)(gch + 2 * p + c2) * HW;
                    const float v = wA * rp2[cy0 * WW + cx0] + wB * rp2[cy0 * WW + cx1]
                                  + wC * rp2[cy1 * WW + cx0] + wD * rp2[cy1 * WW + cx1];
                    acc[s] += (c2 ? (float)lv.y : (float)lv.x) * v;
                }
            }
        }
    }

    float* ob = out + ((size_t)(n * GG + g) * SS) * HW + pix;
#pragma unroll
    for (int s = 0; s < SS; ++s)
        ob[s * HW] = acc[s] * (1.0f / CG);
}

extern "C" void kernel_launch(void* const* d_in, const int* in_sizes, int n_in,
                              void* d_out, int out_size, void* d_ws, size_t ws_size,
                              hipStream_t stream) {
    const float* left  = (const float*)d_in[0];
    const float* right = (const float*)d_in[1];
    const float* eo    = (const float*)d_in[2];
    float* out = (float*)d_out;
    (void)d_ws; (void)ws_size; (void)in_sizes; (void)n_in; (void)out_size;

    dim3 grid(NB * (HH / TY) * GG);   // 256 blocks: (n, h-tile, group)
    dim3 block(1024);                  // 16 waves; thread = (hh, w)
    corr_kernel<<<grid, block, 0, stream>>>(left, right, eo, out);
}

// Round 18
// 21.141 us; speedup vs baseline: 2.1547x; 1.1951x over previous
//
#include <hip/hip_runtime.h>
#include <stdint.h>

// Deformable 3x3 local correlation. f16 channel-major SPLIT-CELL LDS:
// for (row, col c): planes 0-3 (ch0..7 as 4 pair-dwords) at dword 4c of the
// row's lo-half, planes 4-7 at HALF+4c. Every bilinear tap = one aligned
// ds_read_b128 per half -> 8 b128 per s = 72/thread (r15 had 144 ds_read2).
// Bank start = 4c mod 32 -> consecutive lanes stride 4 -> all 32 banks.
// All 16 channels resident (135KB LDS) -> 2 barriers, no double-buffer.
// r16 lesson: unaligned cells kill b128; this layout keeps 16B alignment.
// r6-r13 lesson: 64-VGPR cap not overridable; WRITE_SIZE >> 9.2MB = spill.
// left/right (2,128,64,256) f32, extra_offset (2,18,64,256) f32,
// out (2,72,64,256) f32. GROUPS=8, cg=16, S=9.

#define NB 2
#define CC 128
#define HH 64
#define WW 256
#define GG 8
#define CG 16
#define SS 9
#define HW (HH * WW)
#define TY 4                      // output rows per block
#define RW 5                      // staged rows h0-RW .. h0+TY+RW-1 (14 interior)
#define NSLOT 16                  // 1 top guard + 14 data + 1 bottom guard
#define HALFDW 1056               // dwords per half-row (258 cells x 4dw, padded, mult 32)
#define SLOTQ (2 * HALFDW)        // 2112 dwords per row slot
#define SMEMDW (NSLOT * SLOTQ)    // 33792 dw = 135.2 KB -> 1 block/CU

typedef __fp16 h2v __attribute__((ext_vector_type(2)));

static __device__ __forceinline__ uint32_t pkrtz(float a, float b) {
    h2v v = __builtin_amdgcn_cvt_pkrtz(a, b);
    return __builtin_bit_cast(uint32_t, v);
}
static __device__ __forceinline__ h2v u2h(uint32_t u) {
    return __builtin_bit_cast(h2v, u);
}

#if __has_builtin(__builtin_amdgcn_fdot2)
#define FDOT2(A, B, C) __builtin_amdgcn_fdot2((A), (B), (C), false)
#else
#define FDOT2(A, B, C) fmaf((float)(A).x, (float)(B).x, \
                            fmaf((float)(A).y, (float)(B).y, (C)))
#endif

// 16-channel dot at one (row,col): lo b128 (pairs 0-3) + hi b128 (pairs 4-7)
#define DOT16(LOP, RES)                                                        \
  {                                                                            \
    const uint4 u0_ = *(const uint4*)(LOP);                                    \
    const uint4 u1_ = *(const uint4*)((LOP) + HALFDW);                         \
    RES = FDOT2(u2h(u0_.x), u2h(lvpk[0]),                                      \
          FDOT2(u2h(u0_.y), u2h(lvpk[1]),                                      \
          FDOT2(u2h(u0_.z), u2h(lvpk[2]),                                      \
          FDOT2(u2h(u0_.w), u2h(lvpk[3]),                                      \
          FDOT2(u2h(u1_.x), u2h(lvpk[4]),                                      \
          FDOT2(u2h(u1_.y), u2h(lvpk[5]),                                      \
          FDOT2(u2h(u1_.z), u2h(lvpk[6]),                                      \
          FDOT2(u2h(u1_.w), u2h(lvpk[7]), 0.0f))))))));                        \
  }

__global__ __launch_bounds__(1024) void corr_kernel(
    const float* __restrict__ left, const float* __restrict__ right,
    const float* __restrict__ eo, float* __restrict__ out)
{
    __shared__ uint32_t smem[SMEMDW];

    const int tid = threadIdx.x;
    const int lane = tid & 63;
    const int wv = tid >> 6;                 // wave 0..15
    const int bid = blockIdx.x;
    const int g = bid & (GG - 1);
    const int h0 = ((bid >> 3) & 15) << 2;
    const int n = bid >> 7;
    const int gch = g * CG;

    const int virt_row0 = h0 - RW;                        // slot 1 maps here
    const int row0 = max(0, virt_row0);
    const int row_last = min(HH - 1, h0 + TY + RW - 1);   // h0+8 interior
    const int nrows = row_last - row0 + 1;                // <= 14
    const int sbase = row0 - virt_row0 + 1;

    const int hh = tid >> 8;                 // 0..3 (wave-uniform)
    const int h = h0 + hh;
    const int wcol = tid & 255;
    const int pix = h * WW + wcol;

    const float* rnb = right + (size_t)n * CC * HW;
    const float* lp  = left  + (size_t)(n * CC + gch) * HW + pix;
    const float* eob = eo + (size_t)n * SS * 2 * HW + pix;

    // zero LDS (guard slots/cols + pads must read f16 0.0 = 0x0000)
    for (int i = tid; i < SMEMDW / 4; i += 1024)
        *(uint4*)&smem[4 * i] = make_uint4(0u, 0u, 0u, 0u);
    __syncthreads();

    // stage: wave wv = window row wv; lane covers cols cq = 64*pass + lane.
    // 16 coalesced dword loads (one per channel) -> 8 pkrtz -> 2 b128 writes.
#pragma unroll
    for (int pass = 0; pass < 4; ++pass) {
        if (wv < nrows) {
            const int cq = 64 * pass + lane;             // col 0..255
            const float* s0 = rnb + (size_t)gch * HW + (row0 + wv) * WW + cq;
            uint32_t pk8[8];
#pragma unroll
            for (int p = 0; p < 8; ++p)
                pk8[p] = pkrtz(s0[(size_t)(2 * p) * HW],
                               s0[(size_t)(2 * p + 1) * HW]);
            uint32_t* dst = &smem[(sbase + wv) * SLOTQ + 4 * (cq + 1)];
            *(uint4*)dst            = make_uint4(pk8[0], pk8[1], pk8[2], pk8[3]);
            *(uint4*)(dst + HALFDW) = make_uint4(pk8[4], pk8[5], pk8[6], pk8[7]);
        }
    }

    // left values, packed per pair
    uint32_t lvpk[8];
#pragma unroll
    for (int p = 0; p < 8; ++p)
        lvpk[p] = pkrtz(lp[(size_t)(2 * p) * HW], lp[(size_t)(2 * p + 1) * HW]);

    __syncthreads();                 // planes staged; no more barriers

    float acc[SS];
#pragma unroll
    for (int s = 0; s < SS; ++s) acc[s] = 0.0f;

#pragma unroll
    for (int s = 0; s < SS; ++s) {
        const float x = (float)(s / 3 - 1) + eob[(2 * s) * HW] + (float)wcol;
        const float y = (float)(s % 3 - 1) + eob[(2 * s + 1) * HW] + (float)h;
        const float x0f = floorf(x), y0f = floorf(y);
        const float fx0 = x - x0f, fx1 = 1.0f - fx0;
        const float fy0 = y - y0f, fy1 = 1.0f - fy0;
        const int x0 = (int)x0f, y0 = (int)y0f;
        const int x1 = x0 + 1,   y1 = y0 + 1;
        const bool vx0 = (unsigned)x0 < (unsigned)WW;
        const bool vx1 = (unsigned)x1 < (unsigned)WW;
        const bool vy0 = (unsigned)y0 < (unsigned)HH;
        const bool vy1 = (unsigned)y1 < (unsigned)HH;
        const float wA = (vx0 && vy0) ? fx1 * fy1 : 0.0f;   // (x0,y0)
        const float wB = (vx1 && vy0) ? fx0 * fy1 : 0.0f;   // (x1,y0)
        const float wC = (vx0 && vy1) ? fx1 * fy0 : 0.0f;   // (x0,y1)
        const float wD = (vx1 && vy1) ? fx0 * fy0 : 0.0f;   // (x1,y1)

        const bool bad = (vy0 && (y0 < row0 || y0 > row_last)) ||
                         (vy1 && (y1 < row0 || y1 > row_last));

        if (__builtin_expect(!bad, 1)) {
            const int xc = min(max(x0, -1), WW);                       // [-1,256]
            const int rr = min(max(y0 - virt_row0 + 1, 0), NSLOT - 2); // [0,14]
            const uint32_t* rp0 = smem + rr * SLOTQ + 4 * (xc + 1);
            const uint32_t* rp1 = rp0 + SLOTQ;
            float dA, dB, dC, dD;
            DOT16(rp0,     dA)        // (x0,y0)
            DOT16(rp0 + 4, dB)        // (x1,y0)
            DOT16(rp1,     dC)        // (x0,y1)
            DOT16(rp1 + 4, dD)        // (x1,y1)
            acc[s] += fmaf(wA, dA, fmaf(wB, dB, fmaf(wC, dC, wD * dD)));
        } else {
            // ~never (needs |eo| > ~4.5 sigma): full-precision global fallback
            const int cx0 = min(max(x0, 0), WW - 1), cx1 = min(max(x1, 0), WW - 1);
            const int cy0 = min(max(y0, 0), HH - 1), cy1 = min(max(y1, 0), HH - 1);
#pragma unroll
            for (int p = 0; p < 8; ++p) {
                const h2v lv = u2h(lvpk[p]);
#pragma unroll
                for (int c2 = 0; c2 < 2; ++c2) {
                    const float* rp2 = rnb + (size_t)(gch + 2 * p + c2) * HW;
                    const float v = wA * rp2[cy0 * WW + cx0] + wB * rp2[cy0 * WW + cx1]
                                  + wC * rp2[cy1 * WW + cx0] + wD * rp2[cy1 * WW + cx1];
                    acc[s] += (c2 ? (float)lv.y : (float)lv.x) * v;
                }
            }
        }
    }

    float* ob = out + ((size_t)(n * GG + g) * SS) * HW + pix;
#pragma unroll
    for (int s = 0; s < SS; ++s)
        ob[s * HW] = acc[s] * (1.0f / CG);
}

extern "C" void kernel_launch(void* const* d_in, const int* in_sizes, int n_in,
                              void* d_out, int out_size, void* d_ws, size_t ws_size,
                              hipStream_t stream) {
    const float* left  = (const float*)d_in[0];
    const float* right = (const float*)d_in[1];
    const float* eo    = (const float*)d_in[2];
    float* out = (float*)d_out;
    (void)d_ws; (void)ws_size; (void)in_sizes; (void)n_in; (void)out_size;

    dim3 grid(NB * (HH / TY) * GG);   // 256 blocks: (n, h-tile, group)
    dim3 block(1024);                  // 16 waves; thread = (hh, w)
    corr_kernel<<<grid, block, 0, stream>>>(left, right, eo, out);
}